// Round 16
// baseline (41.035 us; speedup 1.0000x reference)
//
#include <hip/hip_runtime.h>
#include <math.h>
#include <stdint.h>

#define NHEAD 4
#define DD 100
#define NW 39            // word rows
#define SITES 4800

typedef float v2f __attribute__((ext_vector_type(2)));
typedef __attribute__((address_space(3))) uint32_t lds_t;
typedef const __attribute__((address_space(1))) uint32_t glb_t;

// ---------- kernel 1: scores + softmax -> att[site][40][4] (normalized) ----------
__global__ __launch_bounds__(256, 6) void k_att(
    const float* __restrict__ x,       // [4800][40][100]
    const float* __restrict__ w_att,   // [4][100]
    const float* __restrict__ b_att,   // [4][100]
    float* __restrict__ att)           // [4800][40][4] (rows 39 unused)
{
    __shared__ float tile[40 * DD];    // 16 KB

    const int tid  = threadIdx.x;
    const int wv   = __builtin_amdgcn_readfirstlane(tid >> 6);  // wave = head
    const int lane = tid & 63;
    const float* xsite = x + (size_t)blockIdx.x * (40 * DD);

    #pragma unroll
    for (int i = 0; i < 4; ++i) {
        const int cf = i * 256 + tid;
        if (cf < 1000) {
            glb_t* g = (glb_t*)(xsite + cf * 4);
            lds_t* l = (lds_t*)(tile + (i * 256 + wv * 64) * 4);
            __builtin_amdgcn_global_load_lds(g, l, 16, 0, 0);
        }
    }
    __syncthreads();                   // the only barrier

    // Phase A: lane = n, this wave's single head, all 25 chunks
    // leaky(p) = max(p, 0.3p)
    const bool act  = lane < NW;
    const int  nrow = act ? lane : NW - 1;
    const float* wrow = tile + (1 + nrow) * DD;

    v2f accA = {0.f, 0.f}, accB = {0.f, 0.f};
    #pragma unroll
    for (int c = 0; c < 25; ++c) {
        const v2f x01 = *(const v2f*)(wrow + c * 4);            // ds_read (b128 pair)
        const v2f x23 = *(const v2f*)(wrow + c * 4 + 2);
        const v2f t01 = *(const v2f*)(xsite + c * 4);           // uniform s_load
        const v2f t23 = *(const v2f*)(xsite + c * 4 + 2);
        const v2f w01 = *(const v2f*)(w_att + wv * DD + c * 4); // uniform s_load
        const v2f w23 = *(const v2f*)(w_att + wv * DD + c * 4 + 2);
        const v2f b01 = *(const v2f*)(b_att + wv * DD + c * 4);
        const v2f b23 = *(const v2f*)(b_att + wv * DD + c * 4 + 2);
        const v2f p01 = x01 * w01 + b01;
        const v2f p23 = x23 * w23 + b23;
        const v2f l01 = __builtin_elementwise_max(p01, 0.3f * p01);
        const v2f l23 = __builtin_elementwise_max(p23, 0.3f * p23);
        accA = t01 * l01 + accA;
        accB = t23 * l23 + accB;
    }
    const float sc = (accA.x + accA.y) + (accB.x + accB.y);

    // Phase B: raw exp (reference math) + wave sum + normalize
    const float e = act ? __expf(sc) : 0.f;
    float sm = e;
    #pragma unroll
    for (int off = 32; off; off >>= 1) sm += __shfl_xor(sm, off);
    const float a = e / sm;
    if (act) att[(size_t)blockIdx.x * 160 + lane * 4 + wv] = a;
}

// ---------- kernel 2: out[site][h][d] = sum_n att[n][h] * words[n][d] ----------
__global__ __launch_bounds__(256, 4) void k_out(
    const float* __restrict__ x,       // [4800][40][100]
    const float* __restrict__ att,     // [4800][40][4]
    float* __restrict__ out)           // [4800][400]
{
    const int tid  = threadIdx.x;
    const int wv   = __builtin_amdgcn_readfirstlane(tid >> 6);
    const int lane = tid & 63;
    const int site = blockIdx.x * 4 + wv;        // one site per wave; 1200 blocks exact

    // lane n holds att[n][0..3] (one coalesced b128); lanes >=39 clamp (unused)
    const int nl = lane < NW ? lane : NW - 1;
    const float4 at4 = *(const float4*)(att + (size_t)site * 160 + nl * 4);

    // lane = d-pair (50 active); words rows coalesced from global (L3-resident)
    const int l2 = lane < 50 ? lane : 49;
    const float* wb = x + (size_t)site * (40 * DD) + DD + l2 * 2;

    v2f o0 = {0,0}, o1 = {0,0}, o2 = {0,0}, o3 = {0,0};
    #pragma unroll
    for (int n = 0; n < NW; ++n) {
        const v2f wd = *(const v2f*)(wb + n * DD);   // 50-lane coalesced b64
        const float a0 = __builtin_bit_cast(float,
            __builtin_amdgcn_readlane(__builtin_bit_cast(int, at4.x), n));
        const float a1 = __builtin_bit_cast(float,
            __builtin_amdgcn_readlane(__builtin_bit_cast(int, at4.y), n));
        const float a2 = __builtin_bit_cast(float,
            __builtin_amdgcn_readlane(__builtin_bit_cast(int, at4.z), n));
        const float a3 = __builtin_bit_cast(float,
            __builtin_amdgcn_readlane(__builtin_bit_cast(int, at4.w), n));
        o0 = a0 * wd + o0;                           // v_pk_fma, SGPR broadcast
        o1 = a1 * wd + o1;
        o2 = a2 * wd + o2;
        o3 = a3 * wd + o3;
    }
    if (lane < 50) {
        float* ob = out + (size_t)site * (NHEAD * DD) + lane * 2;
        *(v2f*)(ob)          = o0;
        *(v2f*)(ob + DD)     = o1;
        *(v2f*)(ob + 2 * DD) = o2;
        *(v2f*)(ob + 3 * DD) = o3;
    }
}

extern "C" void kernel_launch(void* const* d_in, const int* in_sizes, int n_in,
                              void* d_out, int out_size, void* d_ws, size_t ws_size,
                              hipStream_t stream) {
    const float* x     = (const float*)d_in[0];
    const float* w_att = (const float*)d_in[1];
    const float* b_att = (const float*)d_in[2];
    float* out = (float*)d_out;
    float* att = (float*)d_ws;                   // 4800*160*4 B = 3.07 MB scratch

    k_att<<<SITES, 256, 0, stream>>>(x, w_att, b_att, att);
    k_out<<<SITES / 4, 256, 0, stream>>>(x, att, out);
}

// Round 17
// 27.789 us; speedup vs baseline: 1.4766x; 1.4766x over previous
//
#include <hip/hip_runtime.h>
#include <math.h>
#include <stdint.h>

#define NHEAD 4
#define DD 100
#define NW 39            // word rows
#define BLOCK 256

typedef float v2f __attribute__((ext_vector_type(2)));
typedef __attribute__((address_space(3))) uint32_t lds_t;
typedef const __attribute__((address_space(1))) uint32_t glb_t;

__global__ __launch_bounds__(BLOCK, 6) void ts_enc(
    const float* __restrict__ x,       // [4800][40][100]
    const float* __restrict__ w_att,   // [4][100]
    const float* __restrict__ b_att,   // [4][100]
    float* __restrict__ out)           // [4800][400]
{
    __shared__ float tile[40 * DD];    // 16 KB: row0 = type_emb, rows 1..39 = words

    const int tid  = threadIdx.x;
    const int wv   = __builtin_amdgcn_readfirstlane(tid >> 6);   // wave = head
    const int lane = tid & 63;
    const float* xsite = x + (size_t)blockIdx.x * (40 * DD);

    // ---- stage site tile: async global->LDS, 16 B/lane, 1000 float4 chunks ----
    #pragma unroll
    for (int i = 0; i < 4; ++i) {
        const int cf = i * BLOCK + tid;
        if (cf < 1000) {
            glb_t* g = (glb_t*)(xsite + cf * 4);
            lds_t* l = (lds_t*)(tile + (i * BLOCK + wv * 64) * 4);
            __builtin_amdgcn_global_load_lds(g, l, 16, 0, 0);
        }
    }
    __syncthreads();                   // the ONLY barrier in the kernel

    // ---- Phase A: wave = head wv; lane = n; all 25 chunks in-wave ----
    // leaky(p) = max(p, 0.3p); te/w/b wave-uniform -> scalar pipe (K$-hot)
    const bool act  = lane < NW;
    const int  nrow = act ? lane : NW - 1;          // clamp idle lanes
    const float* wrow = tile + (1 + nrow) * DD;
    const float* wh = w_att + wv * DD;
    const float* bh = b_att + wv * DD;

    v2f accA = {0.f, 0.f}, accB = {0.f, 0.f};
    #pragma unroll
    for (int c = 0; c < 25; ++c) {
        const v2f x01 = *(const v2f*)(wrow + c * 4);     // ds_read_b64
        const v2f x23 = *(const v2f*)(wrow + c * 4 + 2); // ds_read_b64
        const v2f t01 = *(const v2f*)(xsite + c * 4);    // s_load (uniform)
        const v2f t23 = *(const v2f*)(xsite + c * 4 + 2);
        const v2f w01 = *(const v2f*)(wh + c * 4);       // s_load (uniform)
        const v2f w23 = *(const v2f*)(wh + c * 4 + 2);
        const v2f b01 = *(const v2f*)(bh + c * 4);
        const v2f b23 = *(const v2f*)(bh + c * 4 + 2);
        const v2f p01 = x01 * w01 + b01;
        const v2f p23 = x23 * w23 + b23;
        const v2f l01 = __builtin_elementwise_max(p01, 0.3f * p01);
        const v2f l23 = __builtin_elementwise_max(p23, 0.3f * p23);
        accA = t01 * l01 + accA;
        accB = t23 * l23 + accB;
    }
    const float sc = (accA.x + accA.y) + (accB.x + accB.y);

    // ---- Phase B: raw exp (reference computes exp without max-subtract) ----
    const float e = act ? __expf(sc) : 0.f;         // lane n holds e[head=wv][n]

    // ---- Phase C: lane = d-pair (50 active); att via v_readlane (SGPR feeds
    //      v_pk_fma); denominator folded into the same loop; normalize at store ----
    const int l2 = lane < 50 ? lane : 49;           // clamp idle lanes
    const float* wb = tile + DD + l2 * 2;
    v2f o = {0.f, 0.f};
    float s = 0.f;
    #pragma unroll
    for (int n = 0; n < NW; ++n) {
        const float en = __builtin_bit_cast(float,
            __builtin_amdgcn_readlane(__builtin_bit_cast(int, e), n));
        const v2f wd = *(const v2f*)(wb + n * DD);  // 50-lane b64, ~2-way banks
        o = en * wd + o;                            // v_pk_fma
        s += en;
    }
    const float r = 1.f / s;                        // all-zero site: s=39, o=0 ✓
    if (lane < 50) {
        const v2f q = o * r;
        *(v2f*)(out + (size_t)blockIdx.x * (NHEAD * DD) + wv * DD + lane * 2) = q;
    }
}

extern "C" void kernel_launch(void* const* d_in, const int* in_sizes, int n_in,
                              void* d_out, int out_size, void* d_ws, size_t ws_size,
                              hipStream_t stream) {
    const float* x     = (const float*)d_in[0];
    const float* w_att = (const float*)d_in[1];
    const float* b_att = (const float*)d_in[2];
    float* out = (float*)d_out;

    const int sites = 8 * 30 * 20;   // 4800
    ts_enc<<<sites, BLOCK, 0, stream>>>(x, w_att, b_att, out);
}